// Round 4
// baseline (1360.745 us; speedup 1.0000x reference)
//
#include <hip/hip_runtime.h>

#define N_IN    128
#define DD      256
#define KSEL    4096
#define NBATCH  8
#define NGROUP  16
#define CHUNKS  16          // collect chunks per group
#define SUBCAP  4096        // candidate sub-range per (group,chunk)
#define CAND_CAP (CHUNKS*SUBCAP)
#define WCH     13          // write-kernel chunks per group (13*8192 >= 100000)
#define HSLOTS  4           // global hist replica slots per group
#define K1_CPB  250         // kernel-1 blocks per batch
#define K1_ROWS 400         // rows per kernel-1 block

// monotone map: float ordering -> unsigned ordering
__device__ __forceinline__ unsigned keyOf(float s){
    unsigned b = __float_as_uint(s);
    return (b & 0x80000000u) ? ~b : (b | 0x80000000u);
}

// ---------------------------------------------------------------------------
// Kernel 1: scores + fused 11-bit histogram.
// Block = one batch-chunk of 400 rows (group-aligned). Keys histogrammed from
// registers into LDS, merged to 4-slot global hist with sparse atomics.
// ---------------------------------------------------------------------------
__global__ __launch_bounds__(256) void scores_hist_kernel(
        const float* __restrict__ x, const float* __restrict__ W_fr,
        const float* __restrict__ b_fr, unsigned* __restrict__ keys,
        unsigned* __restrict__ gHist, int N, int R)
{
    const int b   = blockIdx.x / K1_CPB;
    const int c   = blockIdx.x % K1_CPB;
    const int rbase = b * R + c * K1_ROWS;
    const int tid = threadIdx.x;
    const int wave = tid >> 6, lane = tid & 63;

    __shared__ unsigned h0[2048], h1[2048];
    for (int i = tid; i < 2048; i += 256){ h0[i] = 0u; h1[i] = 0u; }
    __syncthreads();

    const int f = 4 * (lane & 31);
    const float w00 = W_fr[(f+0)*2+0], w01 = W_fr[(f+0)*2+1];
    const float w10 = W_fr[(f+1)*2+0], w11 = W_fr[(f+1)*2+1];
    const float w20 = W_fr[(f+2)*2+0], w21 = W_fr[(f+2)*2+1];
    const float w30 = W_fr[(f+3)*2+0], w31 = W_fr[(f+3)*2+1];
    const float bf0 = b_fr[0], bf1 = b_fr[1];

    for (int it = 0; it < K1_ROWS/8; ++it){
        const int r0 = rbase + it*8 + wave*2;   // lanes 0-31: row r0, 32-63: r0+1
        const float4 xv = *reinterpret_cast<const float4*>(x + (size_t)r0 * N_IN + 4*lane);
        double p0 = (double)xv.x*w00 + (double)xv.y*w10 + (double)xv.z*w20 + (double)xv.w*w30;
        double p1 = (double)xv.x*w01 + (double)xv.y*w11 + (double)xv.z*w21 + (double)xv.w*w31;
        #pragma unroll
        for (int off = 16; off; off >>= 1){
            p0 += __shfl_xor(p0, off, 32);
            p1 += __shfl_xor(p1, off, 32);
        }
        const unsigned k0 = keyOf((float)(p0 + bf0));
        const unsigned k1 = keyOf((float)(p1 + bf1));
        const int r = r0 + (lane >> 5);
        if ((lane & 31) == 0){ keys[r]     = k0; atomicAdd(&h0[k0 >> 21], 1u); }
        if ((lane & 31) == 1){ keys[N + r] = k1; atomicAdd(&h1[k1 >> 21], 1u); }
    }
    __syncthreads();
    const int slot = c & (HSLOTS-1);
    unsigned* gh0 = gHist + ((size_t)(2*b)   * HSLOTS + slot) * 2048;
    unsigned* gh1 = gHist + ((size_t)(2*b+1) * HSLOTS + slot) * 2048;
    for (int bin = tid; bin < 2048; bin += 256){
        const unsigned s0 = h0[bin], s1 = h1[bin];
        if (s0) atomicAdd(&gh0[bin], s0);
        if (s1) atomicAdd(&gh1[bin], s1);
    }
}

// ---------------------------------------------------------------------------
// Kernel 2: redundant threshold + candidate collect + per-group last-block
// refine (exact utar and tie index bound T). 16 groups x 16 chunks.
// ---------------------------------------------------------------------------
__global__ __launch_bounds__(1024) void collect_refine_kernel(
        const unsigned* __restrict__ keys, const unsigned* __restrict__ gHist,
        unsigned* __restrict__ gCandCnt, int* __restrict__ cand,
        unsigned* __restrict__ gParams, unsigned* __restrict__ gDone,
        int N, int R)
{
    const int g = blockIdx.x >> 4, ch = blockIdx.x & 15;
    const int b = g >> 1, v = g & 1;
    const unsigned* kk = keys + (size_t)v * N + (size_t)b * R;
    const int tid = threadIdx.x, wave = tid >> 6, lane = tid & 63;

    __shared__ unsigned lh[2048];
    __shared__ unsigned coarse[32];
    __shared__ unsigned sB[2];
    __shared__ unsigned wcnt[16];
    __shared__ unsigned sLoc;
    __shared__ unsigned nccs[CHUNKS];
    __shared__ unsigned sOld;

    // ---- (a) per-group threshold (redundant per block) ----
    {
        const unsigned* gh = gHist + (size_t)g * HSLOTS * 2048;
        for (int bin = tid; bin < 2048; bin += 1024){
            unsigned s = 0;
            #pragma unroll
            for (int sl = 0; sl < HSLOTS; ++sl) s += gh[sl*2048 + bin];
            lh[bin] = s;
        }
        __syncthreads();
        if (tid < 32){ unsigned s = 0; for (int j = 0; j < 64; ++j) s += lh[tid*64+j]; coarse[tid] = s; }
        __syncthreads();
        if (tid == 0){
            unsigned kneed = KSEL, cum = 0; int cb = 31;
            for (; cb > 0; --cb){ if (cum + coarse[cb] >= kneed) break; cum += coarse[cb]; }
            int bin = cb*64 + 63;
            for (; bin > cb*64; --bin){ if (cum + lh[bin] >= kneed) break; cum += lh[bin]; }
            sB[0] = (unsigned)bin; sB[1] = kneed - cum;
        }
        __syncthreads();
    }
    const unsigned B1 = sB[0], kneed1 = sB[1];

    // ---- (b) collect this chunk's boundary-bucket candidates ----
    {
        int* cd = cand + (size_t)g * CAND_CAP + ch * SUBCAP;
        const int span = R / CHUNKS;
        const int lo = ch * span, hi = lo + span;
        if (tid == 0) sLoc = 0u;
        __syncthreads();
        for (int i0 = lo; i0 < hi; i0 += 1024){
            const int i = i0 + tid;
            const bool pred = (i < hi) && ((kk[i] >> 21) == B1);
            unsigned long long m = __ballot(pred);
            if (lane == 0) wcnt[wave] = (unsigned)__popcll(m);
            __syncthreads();
            unsigned pre = sLoc, tot = 0;
            #pragma unroll
            for (int w = 0; w < 16; ++w){ unsigned cc = wcnt[w]; if (w < wave) pre += cc; tot += cc; }
            if (pred){
                const unsigned p = pre + (unsigned)__popcll(m & ((1ULL << lane) - 1ULL));
                if (p < (unsigned)SUBCAP) cd[p] = i;
            }
            __syncthreads();
            if (tid == 0) sLoc += tot;
            __syncthreads();
        }
        if (tid == 0) gCandCnt[g*CHUNKS + ch] = min(sLoc, (unsigned)SUBCAP);
    }

    // ---- (c) last chunk of this group refines ----
    __threadfence();
    if (tid == 0) sOld = atomicAdd(&gDone[g], 1u);
    __syncthreads();
    if (sOld != CHUNKS-1) return;
    __threadfence();   // acquire

    if (tid < CHUNKS) nccs[tid] = gCandCnt[g*CHUNKS + tid];
    const int* cd0 = cand + (size_t)g * CAND_CAP;

    // phase B: bits 20..10 (descending)
    for (int i = tid; i < 2048; i += 1024) lh[i] = 0u;
    __syncthreads();
    for (int ch2 = 0; ch2 < CHUNKS; ++ch2){
        const int n = (int)nccs[ch2]; const int* cd = cd0 + ch2*SUBCAP;
        for (int i = tid; i < n; i += 1024)
            atomicAdd(&lh[(kk[cd[i]] >> 10) & 0x7FFu], 1u);
    }
    __syncthreads();
    if (tid < 32){ unsigned s = 0; for (int j = 0; j < 64; ++j) s += lh[tid*64+j]; coarse[tid] = s; }
    __syncthreads();
    if (tid == 0){
        unsigned kneed = kneed1, cum = 0; int cb = 31;
        for (; cb > 0; --cb){ if (cum + coarse[cb] >= kneed) break; cum += coarse[cb]; }
        int bin = cb*64 + 63;
        for (; bin > cb*64; --bin){ if (cum + lh[bin] >= kneed) break; cum += lh[bin]; }
        sB[0] = (unsigned)bin; sB[1] = kneed - cum;
    }
    __syncthreads();
    const unsigned B2 = sB[0], kneed2 = sB[1];
    const unsigned top22 = (B1 << 11) | B2;
    __syncthreads();

    // phase C: low 10 bits (descending)
    for (int i = tid; i < 1024; i += 1024) lh[i] = 0u;
    __syncthreads();
    for (int ch2 = 0; ch2 < CHUNKS; ++ch2){
        const int n = (int)nccs[ch2]; const int* cd = cd0 + ch2*SUBCAP;
        for (int i = tid; i < n; i += 1024){
            const unsigned u = kk[cd[i]];
            if ((u >> 10) == top22) atomicAdd(&lh[u & 0x3FFu], 1u);
        }
    }
    __syncthreads();
    if (tid < 32){ unsigned s = 0; for (int j = 0; j < 32; ++j) s += lh[tid*32+j]; coarse[tid] = s; }
    __syncthreads();
    if (tid == 0){
        unsigned kneed = kneed2, cum = 0; int cb = 31;
        for (; cb > 0; --cb){ if (cum + coarse[cb] >= kneed) break; cum += coarse[cb]; }
        int bin = cb*32 + 31;
        for (; bin > cb*32; --bin){ if (cum + lh[bin] >= kneed) break; cum += lh[bin]; }
        sB[0] = (unsigned)bin; sB[1] = kneed - cum;
    }
    __syncthreads();
    const unsigned B3 = sB[0], take_eq = sB[1];
    const unsigned utar = (B1 << 21) | (B2 << 10) | B3;
    __syncthreads();

    // phase T1: hist of idx>>7 among ties (ascending)
    for (int i = tid; i < 1024; i += 1024) lh[i] = 0u;
    __syncthreads();
    for (int ch2 = 0; ch2 < CHUNKS; ++ch2){
        const int n = (int)nccs[ch2]; const int* cd = cd0 + ch2*SUBCAP;
        for (int i = tid; i < n; i += 1024){
            const int ix = cd[i];
            if (kk[ix] == utar) atomicAdd(&lh[ix >> 7], 1u);
        }
    }
    __syncthreads();
    if (tid < 32){ unsigned s = 0; for (int j = 0; j < 32; ++j) s += lh[tid*32+j]; coarse[tid] = s; }
    __syncthreads();
    if (tid == 0){
        unsigned need = take_eq, cum = 0; int cb = 0;
        for (; cb < 31; ++cb){ if (cum + coarse[cb] >= need) break; cum += coarse[cb]; }
        int bin = cb*32;
        for (; bin < cb*32+31; ++bin){ if (cum + lh[bin] >= need) break; cum += lh[bin]; }
        sB[0] = (unsigned)bin; sB[1] = need - cum;
    }
    __syncthreads();
    const unsigned cb7 = sB[0], rem = sB[1];
    __syncthreads();

    // phase T2: low 7 index bits (ascending)
    for (int i = tid; i < 128; i += 1024) lh[i] = 0u;
    __syncthreads();
    for (int ch2 = 0; ch2 < CHUNKS; ++ch2){
        const int n = (int)nccs[ch2]; const int* cd = cd0 + ch2*SUBCAP;
        for (int i = tid; i < n; i += 1024){
            const int ix = cd[i];
            if (kk[ix] == utar && (unsigned)(ix >> 7) == cb7) atomicAdd(&lh[ix & 127], 1u);
        }
    }
    __syncthreads();
    if (tid == 0){
        unsigned need = rem, cum = 0; int p = 0;
        for (; p < 127; ++p){ if (cum + lh[p] >= need) break; cum += lh[p]; }
        gParams[g*8+2] = utar;
        gParams[g*8+3] = cb7*128 + (unsigned)p;   // T
    }
}

// ---------------------------------------------------------------------------
// Kernel 3: mask write + fused gather of selected rows into fp64 partial sums
// (per group-chunk); global last block runs the tiny MLP -> upd.
// ---------------------------------------------------------------------------
__global__ __launch_bounds__(1024) void write_gather_mlp_kernel(
        const unsigned* __restrict__ keys, const unsigned* __restrict__ gParams,
        const float* __restrict__ x, unsigned char* __restrict__ mask,
        double* __restrict__ part,
        const float* __restrict__ W1, const float* __restrict__ b1,
        const float* __restrict__ W2, const float* __restrict__ b2,
        float* __restrict__ upd, unsigned* __restrict__ wDone,
        int N, int R)
{
    const int g = blockIdx.x / WCH, c = blockIdx.x % WCH;
    const int b = g >> 1, v = g & 1;
    const unsigned* kk = keys + (size_t)v * N + (size_t)b * R;
    unsigned char* mk = mask + (size_t)v * N + (size_t)b * R;
    const unsigned utar = gParams[g*8+2];
    const int T = (int)gParams[g*8+3];
    const int tid = threadIdx.x, wave = tid >> 6, lane = tid & 63;
    const int s = tid >> 5;              // row slot 0..31
    const int c4 = (tid & 31) * 4;       // column group
    const float* xb = x + (size_t)b * R * N_IN;

    __shared__ int slist[1024];
    __shared__ unsigned wcnt[16];
    __shared__ double red[32][128];
    __shared__ unsigned sOld;

    double a0 = 0.0, a1 = 0.0, a2 = 0.0, a3 = 0.0;

    for (int sub = 0; sub < 8; ++sub){
        const int i = c*8192 + sub*1024 + tid;
        const bool valid = i < R;
        const unsigned u = valid ? kk[i] : 0u;
        const bool sel = valid && (u > utar || (u == utar && i <= T));
        if (valid) mk[i] = sel ? (unsigned char)1 : (unsigned char)0;
        unsigned long long m = __ballot(sel);
        if (lane == 0) wcnt[wave] = (unsigned)__popcll(m);
        __syncthreads();
        unsigned pre = 0, tot = 0;
        #pragma unroll
        for (int w = 0; w < 16; ++w){ unsigned cc = wcnt[w]; if (w < wave) pre += cc; tot += cc; }
        if (sel) slist[pre + (unsigned)__popcll(m & ((1ULL << lane) - 1ULL))] = i;
        __syncthreads();
        for (int rr = s; rr < (int)tot; rr += 32){
            const float4 xv = *reinterpret_cast<const float4*>(xb + (size_t)slist[rr] * N_IN + c4);
            a0 += xv.x; a1 += xv.y; a2 += xv.z; a3 += xv.w;
        }
        __syncthreads();
    }

    // cross-slot reduce
    red[s][c4+0] = a0; red[s][c4+1] = a1; red[s][c4+2] = a2; red[s][c4+3] = a3;
    __syncthreads();
    #pragma unroll
    for (int stride = 16; stride >= 1; stride >>= 1){
        if (s < stride){
            red[s][c4+0] += red[s+stride][c4+0];
            red[s][c4+1] += red[s+stride][c4+1];
            red[s][c4+2] += red[s+stride][c4+2];
            red[s][c4+3] += red[s+stride][c4+3];
        }
        __syncthreads();
    }
    if (s == 0){
        double* pp = part + ((size_t)g * WCH + c) * N_IN;
        pp[c4+0] = red[0][c4+0]; pp[c4+1] = red[0][c4+1];
        pp[c4+2] = red[0][c4+2]; pp[c4+3] = red[0][c4+3];
    }

    // ---- global last block: MLP ----
    __threadfence();
    if (tid == 0) sOld = atomicAdd(wDone, 1u);
    __syncthreads();
    if (sOld != (unsigned)(NGROUP*WCH - 1)) return;
    __threadfence();   // acquire

    __shared__ float inv[DD];
    __shared__ float hbuf[DD];
    for (int bb = 0; bb < NBATCH; ++bb){
        if (tid < DD){
            const int g2 = bb*2 + (tid >> 7), fcol = tid & 127;
            double sum = 0.0;
            for (int cc = 0; cc < WCH; ++cc) sum += part[((size_t)g2 * WCH + cc) * N_IN + fcol];
            inv[tid] = (float)(sum / (double)KSEL);
        }
        __syncthreads();
        if (tid < DD){
            float ac[8] = {0,0,0,0,0,0,0,0};
            for (int i8 = 0; i8 < DD; i8 += 8){
                #pragma unroll
                for (int q = 0; q < 8; ++q) ac[q] += inv[i8+q] * W1[(i8+q)*DD + tid];
            }
            const float hsum = ((ac[0]+ac[1])+(ac[2]+ac[3])) + ((ac[4]+ac[5])+(ac[6]+ac[7])) + b1[tid];
            hbuf[tid] = fmaxf(hsum, 0.0f);
        }
        __syncthreads();
        if (tid < DD){
            float ac[8] = {0,0,0,0,0,0,0,0};
            for (int i8 = 0; i8 < DD; i8 += 8){
                #pragma unroll
                for (int q = 0; q < 8; ++q) ac[q] += hbuf[i8+q] * W2[(i8+q)*DD + tid];
            }
            upd[bb*DD + tid] = ((ac[0]+ac[1])+(ac[2]+ac[3])) + ((ac[4]+ac[5])+(ac[6]+ac[7])) + b2[tid];
        }
        __syncthreads();
    }
}

// ---------------------------------------------------------------------------
// Kernel 4: final blend.
// ---------------------------------------------------------------------------
__global__ __launch_bounds__(256) void final_kernel(
        const float* __restrict__ x,
        const unsigned char* __restrict__ mask,
        const float* __restrict__ upd,
        float* __restrict__ out, int N, int R)
{
    const int nvec = N * (N_IN / 4);
    const int stride = gridDim.x * blockDim.x;
    for (int idx = blockIdx.x * blockDim.x + threadIdx.x; idx < nvec; idx += stride){
        const int row = idx >> 5;
        const int c = (idx & 31) * 4;
        float4 o = *reinterpret_cast<const float4*>(x + (size_t)row * N_IN + c);
        const int b = row / R;
        const unsigned char m0 = mask[row];
        const unsigned char m1 = mask[(size_t)N + row];
        if (m0){
            const float4 u0 = *reinterpret_cast<const float4*>(upd + b*DD + c);
            o.x = (o.x + u0.x)*0.5f; o.y = (o.y + u0.y)*0.5f;
            o.z = (o.z + u0.z)*0.5f; o.w = (o.w + u0.w)*0.5f;
        }
        if (m1){
            const float4 u1 = *reinterpret_cast<const float4*>(upd + b*DD + 128 + c);
            o.x = (o.x + u1.x)*0.5f; o.y = (o.y + u1.y)*0.5f;
            o.z = (o.z + u1.z)*0.5f; o.w = (o.w + u1.w)*0.5f;
        }
        *reinterpret_cast<float4*>(out + (size_t)row * N_IN + c) = o;
    }
}

extern "C" void kernel_launch(void* const* d_in, const int* in_sizes, int n_in_cnt,
                              void* d_out, int out_size, void* d_ws, size_t ws_size,
                              hipStream_t stream)
{
    const float* x    = (const float*)d_in[0];
    const float* W_fr = (const float*)d_in[1];
    const float* b_fr = (const float*)d_in[2];
    const float* W1   = (const float*)d_in[3];
    const float* b1   = (const float*)d_in[4];
    const float* W2   = (const float*)d_in[5];
    const float* b2   = (const float*)d_in[6];
    float* out = (float*)d_out;

    const int N = in_sizes[0] / N_IN;   // 800000
    const int R = N / NBATCH;           // 100000

    char* ws = (char*)d_ws;
    size_t off = 0;
    auto alloc = [&](size_t bytes) -> void* {
        void* p = ws + off;
        off = (off + bytes + 255) & ~(size_t)255;
        return p;
    };
    // d_out-tail fallback for anything that doesn't fit in ws (all consumers
    // of tail buffers run before final_kernel writes d_out).
    const size_t outBytes = (size_t)out_size * 4;
    char* tail = (char*)d_out + outBytes;
    auto tail_alloc = [&](size_t bytes) -> void* {
        tail -= bytes;
        tail = (char*)((size_t)tail & ~(size_t)255);
        return tail;
    };
    auto big_alloc = [&](size_t bytes) -> void* {
        if (off + bytes <= ws_size) return alloc(bytes);
        return tail_alloc(bytes);
    };

    unsigned char* mask = (unsigned char*)alloc((size_t)2 * N);
    double*   part    = (double*)  alloc((size_t)NGROUP * WCH * N_IN * 8);
    float*    upd     = (float*)   alloc((size_t)NBATCH * DD * 4);
    unsigned* gParams = (unsigned*)alloc((size_t)NGROUP * 8 * 4);
    unsigned* gCandCnt= (unsigned*)alloc((size_t)NGROUP * CHUNKS * 4);

    const size_t zrBytes = 256 + (size_t)NGROUP * HSLOTS * 2048 * 4;  // counters + gHist
    char*     zr     = (char*)    big_alloc(zrBytes);
    unsigned* gDone  = (unsigned*)zr;                 // [0..15]
    unsigned* wDone  = (unsigned*)(zr + 64);          // [0]
    unsigned* gHist  = (unsigned*)(zr + 256);
    unsigned* keys   = (unsigned*)big_alloc((size_t)2 * N * 4);
    int*      cand   = (int*)     big_alloc((size_t)NGROUP * CAND_CAP * 4);

    hipMemsetAsync(zr, 0, zrBytes, stream);
    scores_hist_kernel<<<dim3(NBATCH*K1_CPB), dim3(256), 0, stream>>>(
        x, W_fr, b_fr, keys, gHist, N, R);
    collect_refine_kernel<<<dim3(NGROUP*CHUNKS), dim3(1024), 0, stream>>>(
        keys, gHist, gCandCnt, cand, gParams, gDone, N, R);
    write_gather_mlp_kernel<<<dim3(NGROUP*WCH), dim3(1024), 0, stream>>>(
        keys, gParams, x, mask, part, W1, b1, W2, b2, upd, wDone, N, R);
    final_kernel<<<dim3(2048), dim3(256), 0, stream>>>(x, mask, upd, out, N, R);
}

// Round 5
// 456.913 us; speedup vs baseline: 2.9781x; 2.9781x over previous
//
#include <hip/hip_runtime.h>

#define N_IN    128
#define DD      256
#define KSEL    4096
#define NBATCH  8
#define NGROUP  16
#define CHUNKS  16          // collect chunks per group
#define SUBCAP  4096        // candidate sub-range per (group,chunk)
#define CAND_CAP (CHUNKS*SUBCAP)
#define WCH     13          // gather chunks per group (13*8192 >= 100000)
#define HSLOTS  4           // global hist replica slots per group
#define K1_CPB  250         // kernel-1 blocks per batch
#define K1_ROWS 400         // rows per kernel-1 block

// monotone map: float ordering -> unsigned ordering
__device__ __forceinline__ unsigned keyOf(float s){
    unsigned b = __float_as_uint(s);
    return (b & 0x80000000u) ? ~b : (b | 0x80000000u);
}

// ---------------------------------------------------------------------------
// Kernel 1: scores + fused 11-bit histogram. (unchanged from round 4 — 66 µs)
// ---------------------------------------------------------------------------
__global__ __launch_bounds__(256) void scores_hist_kernel(
        const float* __restrict__ x, const float* __restrict__ W_fr,
        const float* __restrict__ b_fr, unsigned* __restrict__ keys,
        unsigned* __restrict__ gHist, int N, int R)
{
    const int b   = blockIdx.x / K1_CPB;
    const int c   = blockIdx.x % K1_CPB;
    const int rbase = b * R + c * K1_ROWS;
    const int tid = threadIdx.x;
    const int wave = tid >> 6, lane = tid & 63;

    __shared__ unsigned h0[2048], h1[2048];
    for (int i = tid; i < 2048; i += 256){ h0[i] = 0u; h1[i] = 0u; }
    __syncthreads();

    const int f = 4 * (lane & 31);
    const float w00 = W_fr[(f+0)*2+0], w01 = W_fr[(f+0)*2+1];
    const float w10 = W_fr[(f+1)*2+0], w11 = W_fr[(f+1)*2+1];
    const float w20 = W_fr[(f+2)*2+0], w21 = W_fr[(f+2)*2+1];
    const float w30 = W_fr[(f+3)*2+0], w31 = W_fr[(f+3)*2+1];
    const float bf0 = b_fr[0], bf1 = b_fr[1];

    for (int it = 0; it < K1_ROWS/8; ++it){
        const int r0 = rbase + it*8 + wave*2;
        const float4 xv = *reinterpret_cast<const float4*>(x + (size_t)r0 * N_IN + 4*lane);
        double p0 = (double)xv.x*w00 + (double)xv.y*w10 + (double)xv.z*w20 + (double)xv.w*w30;
        double p1 = (double)xv.x*w01 + (double)xv.y*w11 + (double)xv.z*w21 + (double)xv.w*w31;
        #pragma unroll
        for (int off = 16; off; off >>= 1){
            p0 += __shfl_xor(p0, off, 32);
            p1 += __shfl_xor(p1, off, 32);
        }
        const unsigned k0 = keyOf((float)(p0 + bf0));
        const unsigned k1 = keyOf((float)(p1 + bf1));
        const int r = r0 + (lane >> 5);
        if ((lane & 31) == 0){ keys[r]     = k0; atomicAdd(&h0[k0 >> 21], 1u); }
        if ((lane & 31) == 1){ keys[N + r] = k1; atomicAdd(&h1[k1 >> 21], 1u); }
    }
    __syncthreads();
    const int slot = c & (HSLOTS-1);
    unsigned* gh0 = gHist + ((size_t)(2*b)   * HSLOTS + slot) * 2048;
    unsigned* gh1 = gHist + ((size_t)(2*b+1) * HSLOTS + slot) * 2048;
    for (int bin = tid; bin < 2048; bin += 256){
        const unsigned s0 = h0[bin], s1 = h1[bin];
        if (s0) atomicAdd(&gh0[bin], s0);
        if (s1) atomicAdd(&gh1[bin], s1);
    }
}

// ---------------------------------------------------------------------------
// Kernel 2: redundant threshold + candidate collect + per-group last-block
// refine (exact utar and tie index bound T). (unchanged from round 4)
// ---------------------------------------------------------------------------
__global__ __launch_bounds__(1024) void collect_refine_kernel(
        const unsigned* __restrict__ keys, const unsigned* __restrict__ gHist,
        unsigned* __restrict__ gCandCnt, int* __restrict__ cand,
        unsigned* __restrict__ gParams, unsigned* __restrict__ gDone,
        int N, int R)
{
    const int g = blockIdx.x >> 4, ch = blockIdx.x & 15;
    const int b = g >> 1, v = g & 1;
    const unsigned* kk = keys + (size_t)v * N + (size_t)b * R;
    const int tid = threadIdx.x, wave = tid >> 6, lane = tid & 63;

    __shared__ unsigned lh[2048];
    __shared__ unsigned coarse[32];
    __shared__ unsigned sB[2];
    __shared__ unsigned wcnt[16];
    __shared__ unsigned sLoc;
    __shared__ unsigned nccs[CHUNKS];
    __shared__ unsigned sOld;

    // ---- (a) per-group threshold (redundant per block) ----
    {
        const unsigned* gh = gHist + (size_t)g * HSLOTS * 2048;
        for (int bin = tid; bin < 2048; bin += 1024){
            unsigned s = 0;
            #pragma unroll
            for (int sl = 0; sl < HSLOTS; ++sl) s += gh[sl*2048 + bin];
            lh[bin] = s;
        }
        __syncthreads();
        if (tid < 32){ unsigned s = 0; for (int j = 0; j < 64; ++j) s += lh[tid*64+j]; coarse[tid] = s; }
        __syncthreads();
        if (tid == 0){
            unsigned kneed = KSEL, cum = 0; int cb = 31;
            for (; cb > 0; --cb){ if (cum + coarse[cb] >= kneed) break; cum += coarse[cb]; }
            int bin = cb*64 + 63;
            for (; bin > cb*64; --bin){ if (cum + lh[bin] >= kneed) break; cum += lh[bin]; }
            sB[0] = (unsigned)bin; sB[1] = kneed - cum;
        }
        __syncthreads();
    }
    const unsigned B1 = sB[0], kneed1 = sB[1];

    // ---- (b) collect this chunk's boundary-bucket candidates ----
    {
        int* cd = cand + (size_t)g * CAND_CAP + ch * SUBCAP;
        const int span = R / CHUNKS;
        const int lo = ch * span, hi = lo + span;
        if (tid == 0) sLoc = 0u;
        __syncthreads();
        for (int i0 = lo; i0 < hi; i0 += 1024){
            const int i = i0 + tid;
            const bool pred = (i < hi) && ((kk[i] >> 21) == B1);
            unsigned long long m = __ballot(pred);
            if (lane == 0) wcnt[wave] = (unsigned)__popcll(m);
            __syncthreads();
            unsigned pre = sLoc, tot = 0;
            #pragma unroll
            for (int w = 0; w < 16; ++w){ unsigned cc = wcnt[w]; if (w < wave) pre += cc; tot += cc; }
            if (pred){
                const unsigned p = pre + (unsigned)__popcll(m & ((1ULL << lane) - 1ULL));
                if (p < (unsigned)SUBCAP) cd[p] = i;
            }
            __syncthreads();
            if (tid == 0) sLoc += tot;
            __syncthreads();
        }
        if (tid == 0) gCandCnt[g*CHUNKS + ch] = min(sLoc, (unsigned)SUBCAP);
    }

    // ---- (c) last chunk of this group refines ----
    __threadfence();
    if (tid == 0) sOld = atomicAdd(&gDone[g], 1u);
    __syncthreads();
    if (sOld != CHUNKS-1) return;
    __threadfence();   // acquire

    if (tid < CHUNKS) nccs[tid] = gCandCnt[g*CHUNKS + tid];
    const int* cd0 = cand + (size_t)g * CAND_CAP;

    // phase B: bits 20..10 (descending)
    for (int i = tid; i < 2048; i += 1024) lh[i] = 0u;
    __syncthreads();
    for (int ch2 = 0; ch2 < CHUNKS; ++ch2){
        const int n = (int)nccs[ch2]; const int* cd = cd0 + ch2*SUBCAP;
        for (int i = tid; i < n; i += 1024)
            atomicAdd(&lh[(kk[cd[i]] >> 10) & 0x7FFu], 1u);
    }
    __syncthreads();
    if (tid < 32){ unsigned s = 0; for (int j = 0; j < 64; ++j) s += lh[tid*64+j]; coarse[tid] = s; }
    __syncthreads();
    if (tid == 0){
        unsigned kneed = kneed1, cum = 0; int cb = 31;
        for (; cb > 0; --cb){ if (cum + coarse[cb] >= kneed) break; cum += coarse[cb]; }
        int bin = cb*64 + 63;
        for (; bin > cb*64; --bin){ if (cum + lh[bin] >= kneed) break; cum += lh[bin]; }
        sB[0] = (unsigned)bin; sB[1] = kneed - cum;
    }
    __syncthreads();
    const unsigned B2 = sB[0], kneed2 = sB[1];
    const unsigned top22 = (B1 << 11) | B2;
    __syncthreads();

    // phase C: low 10 bits (descending)
    for (int i = tid; i < 1024; i += 1024) lh[i] = 0u;
    __syncthreads();
    for (int ch2 = 0; ch2 < CHUNKS; ++ch2){
        const int n = (int)nccs[ch2]; const int* cd = cd0 + ch2*SUBCAP;
        for (int i = tid; i < n; i += 1024){
            const unsigned u = kk[cd[i]];
            if ((u >> 10) == top22) atomicAdd(&lh[u & 0x3FFu], 1u);
        }
    }
    __syncthreads();
    if (tid < 32){ unsigned s = 0; for (int j = 0; j < 32; ++j) s += lh[tid*32+j]; coarse[tid] = s; }
    __syncthreads();
    if (tid == 0){
        unsigned kneed = kneed2, cum = 0; int cb = 31;
        for (; cb > 0; --cb){ if (cum + coarse[cb] >= kneed) break; cum += coarse[cb]; }
        int bin = cb*32 + 31;
        for (; bin > cb*32; --bin){ if (cum + lh[bin] >= kneed) break; cum += lh[bin]; }
        sB[0] = (unsigned)bin; sB[1] = kneed - cum;
    }
    __syncthreads();
    const unsigned B3 = sB[0], take_eq = sB[1];
    const unsigned utar = (B1 << 21) | (B2 << 10) | B3;
    __syncthreads();

    // phase T1: hist of idx>>7 among ties (ascending)
    for (int i = tid; i < 1024; i += 1024) lh[i] = 0u;
    __syncthreads();
    for (int ch2 = 0; ch2 < CHUNKS; ++ch2){
        const int n = (int)nccs[ch2]; const int* cd = cd0 + ch2*SUBCAP;
        for (int i = tid; i < n; i += 1024){
            const int ix = cd[i];
            if (kk[ix] == utar) atomicAdd(&lh[ix >> 7], 1u);
        }
    }
    __syncthreads();
    if (tid < 32){ unsigned s = 0; for (int j = 0; j < 32; ++j) s += lh[tid*32+j]; coarse[tid] = s; }
    __syncthreads();
    if (tid == 0){
        unsigned need = take_eq, cum = 0; int cb = 0;
        for (; cb < 31; ++cb){ if (cum + coarse[cb] >= need) break; cum += coarse[cb]; }
        int bin = cb*32;
        for (; bin < cb*32+31; ++bin){ if (cum + lh[bin] >= need) break; cum += lh[bin]; }
        sB[0] = (unsigned)bin; sB[1] = need - cum;
    }
    __syncthreads();
    const unsigned cb7 = sB[0], rem = sB[1];
    __syncthreads();

    // phase T2: low 7 index bits (ascending)
    for (int i = tid; i < 128; i += 1024) lh[i] = 0u;
    __syncthreads();
    for (int ch2 = 0; ch2 < CHUNKS; ++ch2){
        const int n = (int)nccs[ch2]; const int* cd = cd0 + ch2*SUBCAP;
        for (int i = tid; i < n; i += 1024){
            const int ix = cd[i];
            if (kk[ix] == utar && (unsigned)(ix >> 7) == cb7) atomicAdd(&lh[ix & 127], 1u);
        }
    }
    __syncthreads();
    if (tid == 0){
        unsigned need = rem, cum = 0; int p = 0;
        for (; p < 127; ++p){ if (cum + lh[p] >= need) break; cum += lh[p]; }
        gParams[g*8+2] = utar;
        gParams[g*8+3] = cb7*128 + (unsigned)p;   // T
    }
}

// ---------------------------------------------------------------------------
// Kernel 3: mask write + fused gather of selected rows into fp64 partial sums
// (per group-chunk). NO single-block tail (round-4's 930 µs pathology removed).
// ---------------------------------------------------------------------------
__global__ __launch_bounds__(1024) void write_gather_kernel(
        const unsigned* __restrict__ keys, const unsigned* __restrict__ gParams,
        const float* __restrict__ x, unsigned char* __restrict__ mask,
        double* __restrict__ part, int N, int R)
{
    const int g = blockIdx.x / WCH, c = blockIdx.x % WCH;
    const int b = g >> 1, v = g & 1;
    const unsigned* kk = keys + (size_t)v * N + (size_t)b * R;
    unsigned char* mk = mask + (size_t)v * N + (size_t)b * R;
    const unsigned utar = gParams[g*8+2];
    const int T = (int)gParams[g*8+3];
    const int tid = threadIdx.x, wave = tid >> 6, lane = tid & 63;
    const int s = tid >> 5;              // row slot 0..31
    const int c4 = (tid & 31) * 4;       // column group
    const float* xb = x + (size_t)b * R * N_IN;

    __shared__ int slist[1024];
    __shared__ unsigned wcnt[16];
    __shared__ double red[32][128];

    double a0 = 0.0, a1 = 0.0, a2 = 0.0, a3 = 0.0;

    for (int sub = 0; sub < 8; ++sub){
        const int i = c*8192 + sub*1024 + tid;
        const bool valid = i < R;
        const unsigned u = valid ? kk[i] : 0u;
        const bool sel = valid && (u > utar || (u == utar && i <= T));
        if (valid) mk[i] = sel ? (unsigned char)1 : (unsigned char)0;
        unsigned long long m = __ballot(sel);
        if (lane == 0) wcnt[wave] = (unsigned)__popcll(m);
        __syncthreads();
        unsigned pre = 0, tot = 0;
        #pragma unroll
        for (int w = 0; w < 16; ++w){ unsigned cc = wcnt[w]; if (w < wave) pre += cc; tot += cc; }
        if (sel) slist[pre + (unsigned)__popcll(m & ((1ULL << lane) - 1ULL))] = i;
        __syncthreads();
        for (int rr = s; rr < (int)tot; rr += 32){
            const float4 xv = *reinterpret_cast<const float4*>(xb + (size_t)slist[rr] * N_IN + c4);
            a0 += xv.x; a1 += xv.y; a2 += xv.z; a3 += xv.w;
        }
        __syncthreads();
    }

    // cross-slot reduce
    red[s][c4+0] = a0; red[s][c4+1] = a1; red[s][c4+2] = a2; red[s][c4+3] = a3;
    __syncthreads();
    #pragma unroll
    for (int stride = 16; stride >= 1; stride >>= 1){
        if (s < stride){
            red[s][c4+0] += red[s+stride][c4+0];
            red[s][c4+1] += red[s+stride][c4+1];
            red[s][c4+2] += red[s+stride][c4+2];
            red[s][c4+3] += red[s+stride][c4+3];
        }
        __syncthreads();
    }
    if (s == 0){
        double* pp = part + ((size_t)g * WCH + c) * N_IN;
        pp[c4+0] = red[0][c4+0]; pp[c4+1] = red[0][c4+1];
        pp[c4+2] = red[0][c4+2]; pp[c4+3] = red[0][c4+3];
    }
}

// ---------------------------------------------------------------------------
// Kernel 4: reduce partials -> virt (/K), then the tiny 2-layer MLP.
// Round-3-proven structure: 8 blocks x 256 threads, fp64.
// ---------------------------------------------------------------------------
__global__ __launch_bounds__(256) void mlp_kernel(
        const double* __restrict__ part,
        const float* __restrict__ W1, const float* __restrict__ b1,
        const float* __restrict__ W2, const float* __restrict__ b2,
        float* __restrict__ upd)
{
    const int b = blockIdx.x, j = threadIdx.x;
    __shared__ float inv[DD];
    __shared__ float h1[DD];
    {
        const int g2 = b*2 + (j >> 7);
        const int f = j & 127;
        double s = 0.0;
        for (int cc = 0; cc < WCH; ++cc) s += part[((size_t)g2 * WCH + cc) * N_IN + f];
        inv[j] = (float)(s / (double)KSEL);
    }
    __syncthreads();
    double acc = 0.0;
    for (int i = 0; i < DD; ++i) acc += (double)inv[i] * (double)W1[i*DD + j];
    h1[j] = fmaxf((float)(acc + (double)b1[j]), 0.0f);
    __syncthreads();
    acc = 0.0;
    for (int i = 0; i < DD; ++i) acc += (double)h1[i] * (double)W2[i*DD + j];
    upd[b*DD + j] = (float)(acc + (double)b2[j]);
}

// ---------------------------------------------------------------------------
// Kernel 5: final blend.
// ---------------------------------------------------------------------------
__global__ __launch_bounds__(256) void final_kernel(
        const float* __restrict__ x,
        const unsigned char* __restrict__ mask,
        const float* __restrict__ upd,
        float* __restrict__ out, int N, int R)
{
    const int nvec = N * (N_IN / 4);
    const int stride = gridDim.x * blockDim.x;
    for (int idx = blockIdx.x * blockDim.x + threadIdx.x; idx < nvec; idx += stride){
        const int row = idx >> 5;
        const int c = (idx & 31) * 4;
        float4 o = *reinterpret_cast<const float4*>(x + (size_t)row * N_IN + c);
        const int b = row / R;
        const unsigned char m0 = mask[row];
        const unsigned char m1 = mask[(size_t)N + row];
        if (m0){
            const float4 u0 = *reinterpret_cast<const float4*>(upd + b*DD + c);
            o.x = (o.x + u0.x)*0.5f; o.y = (o.y + u0.y)*0.5f;
            o.z = (o.z + u0.z)*0.5f; o.w = (o.w + u0.w)*0.5f;
        }
        if (m1){
            const float4 u1 = *reinterpret_cast<const float4*>(upd + b*DD + 128 + c);
            o.x = (o.x + u1.x)*0.5f; o.y = (o.y + u1.y)*0.5f;
            o.z = (o.z + u1.z)*0.5f; o.w = (o.w + u1.w)*0.5f;
        }
        *reinterpret_cast<float4*>(out + (size_t)row * N_IN + c) = o;
    }
}

extern "C" void kernel_launch(void* const* d_in, const int* in_sizes, int n_in_cnt,
                              void* d_out, int out_size, void* d_ws, size_t ws_size,
                              hipStream_t stream)
{
    const float* x    = (const float*)d_in[0];
    const float* W_fr = (const float*)d_in[1];
    const float* b_fr = (const float*)d_in[2];
    const float* W1   = (const float*)d_in[3];
    const float* b1   = (const float*)d_in[4];
    const float* W2   = (const float*)d_in[5];
    const float* b2   = (const float*)d_in[6];
    float* out = (float*)d_out;

    const int N = in_sizes[0] / N_IN;   // 800000
    const int R = N / NBATCH;           // 100000

    char* ws = (char*)d_ws;
    size_t off = 0;
    auto alloc = [&](size_t bytes) -> void* {
        void* p = ws + off;
        off = (off + bytes + 255) & ~(size_t)255;
        return p;
    };
    const size_t outBytes = (size_t)out_size * 4;
    char* tail = (char*)d_out + outBytes;
    auto tail_alloc = [&](size_t bytes) -> void* {
        tail -= bytes;
        tail = (char*)((size_t)tail & ~(size_t)255);
        return tail;
    };
    auto big_alloc = [&](size_t bytes) -> void* {
        if (off + bytes <= ws_size) return alloc(bytes);
        return tail_alloc(bytes);
    };

    unsigned char* mask = (unsigned char*)alloc((size_t)2 * N);
    double*   part    = (double*)  alloc((size_t)NGROUP * WCH * N_IN * 8);
    float*    upd     = (float*)   alloc((size_t)NBATCH * DD * 4);
    unsigned* gParams = (unsigned*)alloc((size_t)NGROUP * 8 * 4);
    unsigned* gCandCnt= (unsigned*)alloc((size_t)NGROUP * CHUNKS * 4);

    const size_t zrBytes = 256 + (size_t)NGROUP * HSLOTS * 2048 * 4;  // counters + gHist
    char*     zr     = (char*)    big_alloc(zrBytes);
    unsigned* gDone  = (unsigned*)zr;                 // [0..15]
    unsigned* gHist  = (unsigned*)(zr + 256);
    unsigned* keys   = (unsigned*)big_alloc((size_t)2 * N * 4);
    int*      cand   = (int*)     big_alloc((size_t)NGROUP * CAND_CAP * 4);

    hipMemsetAsync(zr, 0, zrBytes, stream);
    scores_hist_kernel<<<dim3(NBATCH*K1_CPB), dim3(256), 0, stream>>>(
        x, W_fr, b_fr, keys, gHist, N, R);
    collect_refine_kernel<<<dim3(NGROUP*CHUNKS), dim3(1024), 0, stream>>>(
        keys, gHist, gCandCnt, cand, gParams, gDone, N, R);
    write_gather_kernel<<<dim3(NGROUP*WCH), dim3(1024), 0, stream>>>(
        keys, gParams, x, mask, part, N, R);
    mlp_kernel<<<dim3(NBATCH), dim3(DD), 0, stream>>>(part, W1, b1, W2, b2, upd);
    final_kernel<<<dim3(2048), dim3(256), 0, stream>>>(x, mask, upd, out, N, R);
}

// Round 6
// 392.366 us; speedup vs baseline: 3.4680x; 1.1645x over previous
//
#include <hip/hip_runtime.h>

#define N_IN    128
#define DD      256
#define KSEL    4096
#define NBATCH  8
#define NGROUP  16
#define CHUNKS  16          // collect chunks per group
#define SUBCAP  4096        // candidate sub-range per (group,chunk)
#define CAND_CAP (CHUNKS*SUBCAP)
#define WCH     13          // gather chunks per group (13*8192 >= 100000)
#define HSLOTS  4           // global hist replica slots per group
#define K1_CPB  250         // kernel-1 blocks per batch
#define K1_ROWS 400         // rows per kernel-1 block
#define USLICE  16          // update-kernel slices per group

// monotone map: float ordering -> unsigned ordering
__device__ __forceinline__ unsigned keyOf(float s){
    unsigned b = __float_as_uint(s);
    return (b & 0x80000000u) ? ~b : (b | 0x80000000u);
}

// ---------------------------------------------------------------------------
// Kernel 1: scores + fused 11-bit histogram + x->out copy.
// The float4 each lane already loaded is stored straight to out (coalesced),
// so the final blend only needs to touch selected rows.
// ---------------------------------------------------------------------------
__global__ __launch_bounds__(256) void scores_hist_copy_kernel(
        const float* __restrict__ x, const float* __restrict__ W_fr,
        const float* __restrict__ b_fr, unsigned* __restrict__ keys,
        unsigned* __restrict__ gHist, float* __restrict__ out, int N, int R)
{
    const int b   = blockIdx.x / K1_CPB;
    const int c   = blockIdx.x % K1_CPB;
    const int rbase = b * R + c * K1_ROWS;
    const int tid = threadIdx.x;
    const int wave = tid >> 6, lane = tid & 63;

    __shared__ unsigned h0[2048], h1[2048];
    for (int i = tid; i < 2048; i += 256){ h0[i] = 0u; h1[i] = 0u; }
    __syncthreads();

    const int f = 4 * (lane & 31);
    const float w00 = W_fr[(f+0)*2+0], w01 = W_fr[(f+0)*2+1];
    const float w10 = W_fr[(f+1)*2+0], w11 = W_fr[(f+1)*2+1];
    const float w20 = W_fr[(f+2)*2+0], w21 = W_fr[(f+2)*2+1];
    const float w30 = W_fr[(f+3)*2+0], w31 = W_fr[(f+3)*2+1];
    const float bf0 = b_fr[0], bf1 = b_fr[1];

    for (int it = 0; it < K1_ROWS/8; ++it){
        const int r0 = rbase + it*8 + wave*2;
        const size_t base = (size_t)r0 * N_IN + 4*lane;
        const float4 xv = *reinterpret_cast<const float4*>(x + base);
        *reinterpret_cast<float4*>(out + base) = xv;       // fused copy
        double p0 = (double)xv.x*w00 + (double)xv.y*w10 + (double)xv.z*w20 + (double)xv.w*w30;
        double p1 = (double)xv.x*w01 + (double)xv.y*w11 + (double)xv.z*w21 + (double)xv.w*w31;
        #pragma unroll
        for (int off = 16; off; off >>= 1){
            p0 += __shfl_xor(p0, off, 32);
            p1 += __shfl_xor(p1, off, 32);
        }
        const unsigned k0 = keyOf((float)(p0 + bf0));
        const unsigned k1 = keyOf((float)(p1 + bf1));
        const int r = r0 + (lane >> 5);
        if ((lane & 31) == 0){ keys[r]     = k0; atomicAdd(&h0[k0 >> 21], 1u); }
        if ((lane & 31) == 1){ keys[N + r] = k1; atomicAdd(&h1[k1 >> 21], 1u); }
    }
    __syncthreads();
    const int slot = c & (HSLOTS-1);
    unsigned* gh0 = gHist + ((size_t)(2*b)   * HSLOTS + slot) * 2048;
    unsigned* gh1 = gHist + ((size_t)(2*b+1) * HSLOTS + slot) * 2048;
    for (int bin = tid; bin < 2048; bin += 256){
        const unsigned s0 = h0[bin], s1 = h1[bin];
        if (s0) atomicAdd(&gh0[bin], s0);
        if (s1) atomicAdd(&gh1[bin], s1);
    }
}

// ---------------------------------------------------------------------------
// Kernel 2: redundant threshold + candidate collect + per-group last-block
// refine (exact utar and tie index bound T). (unchanged — proven)
// ---------------------------------------------------------------------------
__global__ __launch_bounds__(1024) void collect_refine_kernel(
        const unsigned* __restrict__ keys, const unsigned* __restrict__ gHist,
        unsigned* __restrict__ gCandCnt, int* __restrict__ cand,
        unsigned* __restrict__ gParams, unsigned* __restrict__ gDone,
        int N, int R)
{
    const int g = blockIdx.x >> 4, ch = blockIdx.x & 15;
    const int b = g >> 1, v = g & 1;
    const unsigned* kk = keys + (size_t)v * N + (size_t)b * R;
    const int tid = threadIdx.x, wave = tid >> 6, lane = tid & 63;

    __shared__ unsigned lh[2048];
    __shared__ unsigned coarse[32];
    __shared__ unsigned sB[2];
    __shared__ unsigned wcnt[16];
    __shared__ unsigned sLoc;
    __shared__ unsigned nccs[CHUNKS];
    __shared__ unsigned sOld;

    // ---- (a) per-group threshold (redundant per block) ----
    {
        const unsigned* gh = gHist + (size_t)g * HSLOTS * 2048;
        for (int bin = tid; bin < 2048; bin += 1024){
            unsigned s = 0;
            #pragma unroll
            for (int sl = 0; sl < HSLOTS; ++sl) s += gh[sl*2048 + bin];
            lh[bin] = s;
        }
        __syncthreads();
        if (tid < 32){ unsigned s = 0; for (int j = 0; j < 64; ++j) s += lh[tid*64+j]; coarse[tid] = s; }
        __syncthreads();
        if (tid == 0){
            unsigned kneed = KSEL, cum = 0; int cb = 31;
            for (; cb > 0; --cb){ if (cum + coarse[cb] >= kneed) break; cum += coarse[cb]; }
            int bin = cb*64 + 63;
            for (; bin > cb*64; --bin){ if (cum + lh[bin] >= kneed) break; cum += lh[bin]; }
            sB[0] = (unsigned)bin; sB[1] = kneed - cum;
        }
        __syncthreads();
    }
    const unsigned B1 = sB[0], kneed1 = sB[1];

    // ---- (b) collect this chunk's boundary-bucket candidates ----
    {
        int* cd = cand + (size_t)g * CAND_CAP + ch * SUBCAP;
        const int span = R / CHUNKS;
        const int lo = ch * span, hi = lo + span;
        if (tid == 0) sLoc = 0u;
        __syncthreads();
        for (int i0 = lo; i0 < hi; i0 += 1024){
            const int i = i0 + tid;
            const bool pred = (i < hi) && ((kk[i] >> 21) == B1);
            unsigned long long m = __ballot(pred);
            if (lane == 0) wcnt[wave] = (unsigned)__popcll(m);
            __syncthreads();
            unsigned pre = sLoc, tot = 0;
            #pragma unroll
            for (int w = 0; w < 16; ++w){ unsigned cc = wcnt[w]; if (w < wave) pre += cc; tot += cc; }
            if (pred){
                const unsigned p = pre + (unsigned)__popcll(m & ((1ULL << lane) - 1ULL));
                if (p < (unsigned)SUBCAP) cd[p] = i;
            }
            __syncthreads();
            if (tid == 0) sLoc += tot;
            __syncthreads();
        }
        if (tid == 0) gCandCnt[g*CHUNKS + ch] = min(sLoc, (unsigned)SUBCAP);
    }

    // ---- (c) last chunk of this group refines ----
    __threadfence();
    if (tid == 0) sOld = atomicAdd(&gDone[g], 1u);
    __syncthreads();
    if (sOld != CHUNKS-1) return;
    __threadfence();   // acquire

    if (tid < CHUNKS) nccs[tid] = gCandCnt[g*CHUNKS + tid];
    const int* cd0 = cand + (size_t)g * CAND_CAP;

    // phase B: bits 20..10 (descending)
    for (int i = tid; i < 2048; i += 1024) lh[i] = 0u;
    __syncthreads();
    for (int ch2 = 0; ch2 < CHUNKS; ++ch2){
        const int n = (int)nccs[ch2]; const int* cd = cd0 + ch2*SUBCAP;
        for (int i = tid; i < n; i += 1024)
            atomicAdd(&lh[(kk[cd[i]] >> 10) & 0x7FFu], 1u);
    }
    __syncthreads();
    if (tid < 32){ unsigned s = 0; for (int j = 0; j < 64; ++j) s += lh[tid*64+j]; coarse[tid] = s; }
    __syncthreads();
    if (tid == 0){
        unsigned kneed = kneed1, cum = 0; int cb = 31;
        for (; cb > 0; --cb){ if (cum + coarse[cb] >= kneed) break; cum += coarse[cb]; }
        int bin = cb*64 + 63;
        for (; bin > cb*64; --bin){ if (cum + lh[bin] >= kneed) break; cum += lh[bin]; }
        sB[0] = (unsigned)bin; sB[1] = kneed - cum;
    }
    __syncthreads();
    const unsigned B2 = sB[0], kneed2 = sB[1];
    const unsigned top22 = (B1 << 11) | B2;
    __syncthreads();

    // phase C: low 10 bits (descending)
    for (int i = tid; i < 1024; i += 1024) lh[i] = 0u;
    __syncthreads();
    for (int ch2 = 0; ch2 < CHUNKS; ++ch2){
        const int n = (int)nccs[ch2]; const int* cd = cd0 + ch2*SUBCAP;
        for (int i = tid; i < n; i += 1024){
            const unsigned u = kk[cd[i]];
            if ((u >> 10) == top22) atomicAdd(&lh[u & 0x3FFu], 1u);
        }
    }
    __syncthreads();
    if (tid < 32){ unsigned s = 0; for (int j = 0; j < 32; ++j) s += lh[tid*32+j]; coarse[tid] = s; }
    __syncthreads();
    if (tid == 0){
        unsigned kneed = kneed2, cum = 0; int cb = 31;
        for (; cb > 0; --cb){ if (cum + coarse[cb] >= kneed) break; cum += coarse[cb]; }
        int bin = cb*32 + 31;
        for (; bin > cb*32; --bin){ if (cum + lh[bin] >= kneed) break; cum += lh[bin]; }
        sB[0] = (unsigned)bin; sB[1] = kneed - cum;
    }
    __syncthreads();
    const unsigned B3 = sB[0], take_eq = sB[1];
    const unsigned utar = (B1 << 21) | (B2 << 10) | B3;
    __syncthreads();

    // phase T1: hist of idx>>7 among ties (ascending)
    for (int i = tid; i < 1024; i += 1024) lh[i] = 0u;
    __syncthreads();
    for (int ch2 = 0; ch2 < CHUNKS; ++ch2){
        const int n = (int)nccs[ch2]; const int* cd = cd0 + ch2*SUBCAP;
        for (int i = tid; i < n; i += 1024){
            const int ix = cd[i];
            if (kk[ix] == utar) atomicAdd(&lh[ix >> 7], 1u);
        }
    }
    __syncthreads();
    if (tid < 32){ unsigned s = 0; for (int j = 0; j < 32; ++j) s += lh[tid*32+j]; coarse[tid] = s; }
    __syncthreads();
    if (tid == 0){
        unsigned need = take_eq, cum = 0; int cb = 0;
        for (; cb < 31; ++cb){ if (cum + coarse[cb] >= need) break; cum += coarse[cb]; }
        int bin = cb*32;
        for (; bin < cb*32+31; ++bin){ if (cum + lh[bin] >= need) break; cum += lh[bin]; }
        sB[0] = (unsigned)bin; sB[1] = need - cum;
    }
    __syncthreads();
    const unsigned cb7 = sB[0], rem = sB[1];
    __syncthreads();

    // phase T2: low 7 index bits (ascending)
    for (int i = tid; i < 128; i += 1024) lh[i] = 0u;
    __syncthreads();
    for (int ch2 = 0; ch2 < CHUNKS; ++ch2){
        const int n = (int)nccs[ch2]; const int* cd = cd0 + ch2*SUBCAP;
        for (int i = tid; i < n; i += 1024){
            const int ix = cd[i];
            if (kk[ix] == utar && (unsigned)(ix >> 7) == cb7) atomicAdd(&lh[ix & 127], 1u);
        }
    }
    __syncthreads();
    if (tid == 0){
        unsigned need = rem, cum = 0; int p = 0;
        for (; p < 127; ++p){ if (cum + lh[p] >= need) break; cum += lh[p]; }
        gParams[g*8+2] = utar;
        gParams[g*8+3] = cb7*128 + (unsigned)p;   // T
    }
}

// ---------------------------------------------------------------------------
// Kernel 3: mask write + compact list output + fused gather into fp64 partial
// sums. One list-append atomic per (block,sub) on padded per-group lines.
// ---------------------------------------------------------------------------
__global__ __launch_bounds__(1024) void write_gather_kernel(
        const unsigned* __restrict__ keys, const unsigned* __restrict__ gParams,
        const float* __restrict__ x, unsigned char* __restrict__ mask,
        int* __restrict__ lists, unsigned* __restrict__ gListCnt,
        double* __restrict__ part, int N, int R)
{
    const int g = blockIdx.x / WCH, c = blockIdx.x % WCH;
    const int b = g >> 1, v = g & 1;
    const unsigned* kk = keys + (size_t)v * N + (size_t)b * R;
    unsigned char* mk = mask + (size_t)v * N + (size_t)b * R;
    int* lst = lists + g * KSEL;
    const unsigned utar = gParams[g*8+2];
    const int T = (int)gParams[g*8+3];
    const int tid = threadIdx.x, wave = tid >> 6, lane = tid & 63;
    const int s = tid >> 5;              // row slot 0..31
    const int c4 = (tid & 31) * 4;       // column group
    const float* xb = x + (size_t)b * R * N_IN;

    __shared__ int slist[1024];
    __shared__ unsigned wcnt[16];
    __shared__ unsigned sSubBase;
    __shared__ double red[32][128];

    double a0 = 0.0, a1 = 0.0, a2 = 0.0, a3 = 0.0;

    for (int sub = 0; sub < 8; ++sub){
        const int i = c*8192 + sub*1024 + tid;
        const bool valid = i < R;
        const unsigned u = valid ? kk[i] : 0u;
        const bool sel = valid && (u > utar || (u == utar && i <= T));
        if (valid) mk[i] = sel ? (unsigned char)1 : (unsigned char)0;
        unsigned long long m = __ballot(sel);
        if (lane == 0) wcnt[wave] = (unsigned)__popcll(m);
        __syncthreads();
        unsigned pre = 0, tot = 0;
        #pragma unroll
        for (int w = 0; w < 16; ++w){ unsigned cc = wcnt[w]; if (w < wave) pre += cc; tot += cc; }
        if (tid == 0) sSubBase = tot ? atomicAdd(&gListCnt[g*16], tot) : 0u;
        const unsigned loc = pre + (unsigned)__popcll(m & ((1ULL << lane) - 1ULL));
        if (sel) slist[loc] = i;
        __syncthreads();
        if (sel) lst[sSubBase + loc] = i;
        for (int rr = s; rr < (int)tot; rr += 32){
            const float4 xv = *reinterpret_cast<const float4*>(xb + (size_t)slist[rr] * N_IN + c4);
            a0 += xv.x; a1 += xv.y; a2 += xv.z; a3 += xv.w;
        }
        __syncthreads();
    }

    // cross-slot reduce
    red[s][c4+0] = a0; red[s][c4+1] = a1; red[s][c4+2] = a2; red[s][c4+3] = a3;
    __syncthreads();
    #pragma unroll
    for (int stride = 16; stride >= 1; stride >>= 1){
        if (s < stride){
            red[s][c4+0] += red[s+stride][c4+0];
            red[s][c4+1] += red[s+stride][c4+1];
            red[s][c4+2] += red[s+stride][c4+2];
            red[s][c4+3] += red[s+stride][c4+3];
        }
        __syncthreads();
    }
    if (s == 0){
        double* pp = part + ((size_t)g * WCH + c) * N_IN;
        pp[c4+0] = red[0][c4+0]; pp[c4+1] = red[0][c4+1];
        pp[c4+2] = red[0][c4+2]; pp[c4+3] = red[0][c4+3];
    }
}

// ---------------------------------------------------------------------------
// Kernel 4: reduce partials -> virt (/K), then the tiny 2-layer MLP.
// 8 blocks x 256 threads, fp64 (proven).
// ---------------------------------------------------------------------------
__global__ __launch_bounds__(256) void mlp_kernel(
        const double* __restrict__ part,
        const float* __restrict__ W1, const float* __restrict__ b1,
        const float* __restrict__ W2, const float* __restrict__ b2,
        float* __restrict__ upd)
{
    const int b = blockIdx.x, j = threadIdx.x;
    __shared__ float inv[DD];
    __shared__ float h1[DD];
    {
        const int g2 = b*2 + (j >> 7);
        const int f = j & 127;
        double s = 0.0;
        for (int cc = 0; cc < WCH; ++cc) s += part[((size_t)g2 * WCH + cc) * N_IN + f];
        inv[j] = (float)(s / (double)KSEL);
    }
    __syncthreads();
    double acc = 0.0;
    for (int i = 0; i < DD; ++i) acc += (double)inv[i] * (double)W1[i*DD + j];
    h1[j] = fmaxf((float)(acc + (double)b1[j]), 0.0f);
    __syncthreads();
    acc = 0.0;
    for (int i = 0; i < DD; ++i) acc += (double)h1[i] * (double)W2[i*DD + j];
    upd[b*DD + j] = (float)(acc + (double)b2[j]);
}

// ---------------------------------------------------------------------------
// Kernel 5: sparse blend update — touch only the selected rows.
// v=0 slices handle their rows fully (v0 then v1 if both); v=1 slices skip
// rows also in mask0 (those are handled by the v0 slice). Half-wave = 1 row.
// ---------------------------------------------------------------------------
__global__ __launch_bounds__(256) void update_kernel(
        const float* __restrict__ x, const unsigned char* __restrict__ mask,
        const int* __restrict__ lists, const float* __restrict__ upd,
        float* __restrict__ out, int N, int R)
{
    const int g = blockIdx.x >> 4, sl = blockIdx.x & (USLICE-1);
    const int b = g >> 1, v = g & 1;
    const int tid = threadIdx.x;
    const int wave = tid >> 6, lane = tid & 63;
    const int half = lane >> 5;
    const int c4 = (lane & 31) * 4;
    const int* lst = lists + g * KSEL + sl * (KSEL/USLICE);
    const unsigned char* mk0 = mask + (size_t)b * R;
    const unsigned char* mk1 = mask + (size_t)N + (size_t)b * R;
    const float4 u0 = *reinterpret_cast<const float4*>(upd + b*DD + c4);
    const float4 u1 = *reinterpret_cast<const float4*>(upd + b*DD + 128 + c4);
    const size_t rowBase = (size_t)b * R;

    for (int e = wave*2 + half; e < KSEL/USLICE; e += 8){
        const int row = lst[e];
        if (v == 1 && mk0[row]) continue;          // handled by the v0 pass
        const size_t base = (rowBase + row) * N_IN + c4;
        float4 o = *reinterpret_cast<const float4*>(x + base);
        if (v == 0){
            o.x = (o.x + u0.x)*0.5f; o.y = (o.y + u0.y)*0.5f;
            o.z = (o.z + u0.z)*0.5f; o.w = (o.w + u0.w)*0.5f;
            if (mk1[row]){
                o.x = (o.x + u1.x)*0.5f; o.y = (o.y + u1.y)*0.5f;
                o.z = (o.z + u1.z)*0.5f; o.w = (o.w + u1.w)*0.5f;
            }
        } else {
            o.x = (o.x + u1.x)*0.5f; o.y = (o.y + u1.y)*0.5f;
            o.z = (o.z + u1.z)*0.5f; o.w = (o.w + u1.w)*0.5f;
        }
        *reinterpret_cast<float4*>(out + base) = o;
    }
}

extern "C" void kernel_launch(void* const* d_in, const int* in_sizes, int n_in_cnt,
                              void* d_out, int out_size, void* d_ws, size_t ws_size,
                              hipStream_t stream)
{
    const float* x    = (const float*)d_in[0];
    const float* W_fr = (const float*)d_in[1];
    const float* b_fr = (const float*)d_in[2];
    const float* W1   = (const float*)d_in[3];
    const float* b1   = (const float*)d_in[4];
    const float* W2   = (const float*)d_in[5];
    const float* b2   = (const float*)d_in[6];
    float* out = (float*)d_out;

    const int N = in_sizes[0] / N_IN;   // 800000
    const int R = N / NBATCH;           // 100000

    char* ws = (char*)d_ws;
    size_t off = 0;
    auto alloc = [&](size_t bytes) -> void* {
        void* p = ws + off;
        off = (off + bytes + 255) & ~(size_t)255;
        return p;
    };
    // NOTE: no d_out-tail fallback anymore — kernel 1 now writes ALL of d_out,
    // so scratch must live entirely in d_ws (total ~15 MB, well under ws_size).
    unsigned char* mask = (unsigned char*)alloc((size_t)2 * N);
    int*      lists   = (int*)     alloc((size_t)NGROUP * KSEL * 4);
    double*   part    = (double*)  alloc((size_t)NGROUP * WCH * N_IN * 8);
    float*    upd     = (float*)   alloc((size_t)NBATCH * DD * 4);
    unsigned* gParams = (unsigned*)alloc((size_t)NGROUP * 8 * 4);
    unsigned* gCandCnt= (unsigned*)alloc((size_t)NGROUP * CHUNKS * 4);

    const size_t zrBytes = 256 + 4096 + (size_t)NGROUP * HSLOTS * 2048 * 4;
    char*     zr       = (char*)    alloc(zrBytes);
    unsigned* gDone    = (unsigned*)zr;                  // 16 counters
    unsigned* gListCnt = (unsigned*)(zr + 256);          // 16 groups * 64B lines
    unsigned* gHist    = (unsigned*)(zr + 256 + 4096);
    unsigned* keys     = (unsigned*)alloc((size_t)2 * N * 4);
    int*      cand     = (int*)     alloc((size_t)NGROUP * CAND_CAP * 4);

    hipMemsetAsync(zr, 0, zrBytes, stream);
    scores_hist_copy_kernel<<<dim3(NBATCH*K1_CPB), dim3(256), 0, stream>>>(
        x, W_fr, b_fr, keys, gHist, out, N, R);
    collect_refine_kernel<<<dim3(NGROUP*CHUNKS), dim3(1024), 0, stream>>>(
        keys, gHist, gCandCnt, cand, gParams, gDone, N, R);
    write_gather_kernel<<<dim3(NGROUP*WCH), dim3(1024), 0, stream>>>(
        keys, gParams, x, mask, lists, gListCnt, part, N, R);
    mlp_kernel<<<dim3(NBATCH), dim3(DD), 0, stream>>>(part, W1, b1, W2, b2, upd);
    update_kernel<<<dim3(NGROUP*USLICE), dim3(256), 0, stream>>>(
        x, mask, lists, upd, out, N, R);
}

// Round 7
// 388.406 us; speedup vs baseline: 3.5034x; 1.0102x over previous
//
#include <hip/hip_runtime.h>

#define N_IN    128
#define DD      256
#define KSEL    4096
#define NBATCH  8
#define NGROUP  16
#define CHUNKS  16          // collect chunks per group
#define SUBCAP  4096        // candidate sub-range per (group,chunk)
#define CAND_CAP (CHUNKS*SUBCAP)
#define WCH     13          // gather chunks per group (13*8192 >= 100000)
#define HSLOTS  4           // global hist replica slots per group
#define K1_CPB  250         // kernel-1 blocks per batch
#define K1_ROWS 400         // rows per kernel-1 block
#define USLICE  16          // update-kernel slices per group

// monotone map: float ordering -> unsigned ordering
__device__ __forceinline__ unsigned keyOf(float s){
    unsigned b = __float_as_uint(s);
    return (b & 0x80000000u) ? ~b : (b | 0x80000000u);
}

// ---------------------------------------------------------------------------
// Kernel 0: zero the counter/histogram block (replaces hipMemsetAsync, whose
// rocclr fillBuffer dispatch showed 2.2 GB/s in rocprof).
// ---------------------------------------------------------------------------
__global__ __launch_bounds__(256) void zero_kernel(uint4* __restrict__ p, int n16)
{
    const int i = blockIdx.x * 256 + threadIdx.x;
    if (i < n16) p[i] = uint4{0u, 0u, 0u, 0u};
}

// ---------------------------------------------------------------------------
// Kernel 1: scores + fused 11-bit histogram + x->out copy. (proven)
// ---------------------------------------------------------------------------
__global__ __launch_bounds__(256) void scores_hist_copy_kernel(
        const float* __restrict__ x, const float* __restrict__ W_fr,
        const float* __restrict__ b_fr, unsigned* __restrict__ keys,
        unsigned* __restrict__ gHist, float* __restrict__ out, int N, int R)
{
    const int b   = blockIdx.x / K1_CPB;
    const int c   = blockIdx.x % K1_CPB;
    const int rbase = b * R + c * K1_ROWS;
    const int tid = threadIdx.x;
    const int wave = tid >> 6, lane = tid & 63;

    __shared__ unsigned h0[2048], h1[2048];
    for (int i = tid; i < 2048; i += 256){ h0[i] = 0u; h1[i] = 0u; }
    __syncthreads();

    const int f = 4 * (lane & 31);
    const float w00 = W_fr[(f+0)*2+0], w01 = W_fr[(f+0)*2+1];
    const float w10 = W_fr[(f+1)*2+0], w11 = W_fr[(f+1)*2+1];
    const float w20 = W_fr[(f+2)*2+0], w21 = W_fr[(f+2)*2+1];
    const float w30 = W_fr[(f+3)*2+0], w31 = W_fr[(f+3)*2+1];
    const float bf0 = b_fr[0], bf1 = b_fr[1];

    for (int it = 0; it < K1_ROWS/8; ++it){
        const int r0 = rbase + it*8 + wave*2;
        const size_t base = (size_t)r0 * N_IN + 4*lane;
        const float4 xv = *reinterpret_cast<const float4*>(x + base);
        *reinterpret_cast<float4*>(out + base) = xv;       // fused copy
        double p0 = (double)xv.x*w00 + (double)xv.y*w10 + (double)xv.z*w20 + (double)xv.w*w30;
        double p1 = (double)xv.x*w01 + (double)xv.y*w11 + (double)xv.z*w21 + (double)xv.w*w31;
        #pragma unroll
        for (int off = 16; off; off >>= 1){
            p0 += __shfl_xor(p0, off, 32);
            p1 += __shfl_xor(p1, off, 32);
        }
        const unsigned k0 = keyOf((float)(p0 + bf0));
        const unsigned k1 = keyOf((float)(p1 + bf1));
        const int r = r0 + (lane >> 5);
        if ((lane & 31) == 0){ keys[r]     = k0; atomicAdd(&h0[k0 >> 21], 1u); }
        if ((lane & 31) == 1){ keys[N + r] = k1; atomicAdd(&h1[k1 >> 21], 1u); }
    }
    __syncthreads();
    const int slot = c & (HSLOTS-1);
    unsigned* gh0 = gHist + ((size_t)(2*b)   * HSLOTS + slot) * 2048;
    unsigned* gh1 = gHist + ((size_t)(2*b+1) * HSLOTS + slot) * 2048;
    for (int bin = tid; bin < 2048; bin += 256){
        const unsigned s0 = h0[bin], s1 = h1[bin];
        if (s0) atomicAdd(&gh0[bin], s0);
        if (s1) atomicAdd(&gh1[bin], s1);
    }
}

// ---------------------------------------------------------------------------
// Kernel 2: redundant threshold + candidate collect + per-group last-block
// refine (exact utar and tie index bound T). (proven)
// ---------------------------------------------------------------------------
__global__ __launch_bounds__(1024) void collect_refine_kernel(
        const unsigned* __restrict__ keys, const unsigned* __restrict__ gHist,
        unsigned* __restrict__ gCandCnt, int* __restrict__ cand,
        unsigned* __restrict__ gParams, unsigned* __restrict__ gDone,
        int N, int R)
{
    const int g = blockIdx.x >> 4, ch = blockIdx.x & 15;
    const int b = g >> 1, v = g & 1;
    const unsigned* kk = keys + (size_t)v * N + (size_t)b * R;
    const int tid = threadIdx.x, wave = tid >> 6, lane = tid & 63;

    __shared__ unsigned lh[2048];
    __shared__ unsigned coarse[32];
    __shared__ unsigned sB[2];
    __shared__ unsigned wcnt[16];
    __shared__ unsigned sLoc;
    __shared__ unsigned nccs[CHUNKS];
    __shared__ unsigned sOld;

    // ---- (a) per-group threshold (redundant per block) ----
    {
        const unsigned* gh = gHist + (size_t)g * HSLOTS * 2048;
        for (int bin = tid; bin < 2048; bin += 1024){
            unsigned s = 0;
            #pragma unroll
            for (int sl = 0; sl < HSLOTS; ++sl) s += gh[sl*2048 + bin];
            lh[bin] = s;
        }
        __syncthreads();
        if (tid < 32){ unsigned s = 0; for (int j = 0; j < 64; ++j) s += lh[tid*64+j]; coarse[tid] = s; }
        __syncthreads();
        if (tid == 0){
            unsigned kneed = KSEL, cum = 0; int cb = 31;
            for (; cb > 0; --cb){ if (cum + coarse[cb] >= kneed) break; cum += coarse[cb]; }
            int bin = cb*64 + 63;
            for (; bin > cb*64; --bin){ if (cum + lh[bin] >= kneed) break; cum += lh[bin]; }
            sB[0] = (unsigned)bin; sB[1] = kneed - cum;
        }
        __syncthreads();
    }
    const unsigned B1 = sB[0], kneed1 = sB[1];

    // ---- (b) collect this chunk's boundary-bucket candidates ----
    {
        int* cd = cand + (size_t)g * CAND_CAP + ch * SUBCAP;
        const int span = R / CHUNKS;
        const int lo = ch * span, hi = lo + span;
        if (tid == 0) sLoc = 0u;
        __syncthreads();
        for (int i0 = lo; i0 < hi; i0 += 1024){
            const int i = i0 + tid;
            const bool pred = (i < hi) && ((kk[i] >> 21) == B1);
            unsigned long long m = __ballot(pred);
            if (lane == 0) wcnt[wave] = (unsigned)__popcll(m);
            __syncthreads();
            unsigned pre = sLoc, tot = 0;
            #pragma unroll
            for (int w = 0; w < 16; ++w){ unsigned cc = wcnt[w]; if (w < wave) pre += cc; tot += cc; }
            if (pred){
                const unsigned p = pre + (unsigned)__popcll(m & ((1ULL << lane) - 1ULL));
                if (p < (unsigned)SUBCAP) cd[p] = i;
            }
            __syncthreads();
            if (tid == 0) sLoc += tot;
            __syncthreads();
        }
        if (tid == 0) gCandCnt[g*CHUNKS + ch] = min(sLoc, (unsigned)SUBCAP);
    }

    // ---- (c) last chunk of this group refines ----
    __threadfence();
    if (tid == 0) sOld = atomicAdd(&gDone[g], 1u);
    __syncthreads();
    if (sOld != CHUNKS-1) return;
    __threadfence();   // acquire

    if (tid < CHUNKS) nccs[tid] = gCandCnt[g*CHUNKS + tid];
    const int* cd0 = cand + (size_t)g * CAND_CAP;

    // phase B: bits 20..10 (descending)
    for (int i = tid; i < 2048; i += 1024) lh[i] = 0u;
    __syncthreads();
    for (int ch2 = 0; ch2 < CHUNKS; ++ch2){
        const int n = (int)nccs[ch2]; const int* cd = cd0 + ch2*SUBCAP;
        for (int i = tid; i < n; i += 1024)
            atomicAdd(&lh[(kk[cd[i]] >> 10) & 0x7FFu], 1u);
    }
    __syncthreads();
    if (tid < 32){ unsigned s = 0; for (int j = 0; j < 64; ++j) s += lh[tid*64+j]; coarse[tid] = s; }
    __syncthreads();
    if (tid == 0){
        unsigned kneed = kneed1, cum = 0; int cb = 31;
        for (; cb > 0; --cb){ if (cum + coarse[cb] >= kneed) break; cum += coarse[cb]; }
        int bin = cb*64 + 63;
        for (; bin > cb*64; --bin){ if (cum + lh[bin] >= kneed) break; cum += lh[bin]; }
        sB[0] = (unsigned)bin; sB[1] = kneed - cum;
    }
    __syncthreads();
    const unsigned B2 = sB[0], kneed2 = sB[1];
    const unsigned top22 = (B1 << 11) | B2;
    __syncthreads();

    // phase C: low 10 bits (descending)
    for (int i = tid; i < 1024; i += 1024) lh[i] = 0u;
    __syncthreads();
    for (int ch2 = 0; ch2 < CHUNKS; ++ch2){
        const int n = (int)nccs[ch2]; const int* cd = cd0 + ch2*SUBCAP;
        for (int i = tid; i < n; i += 1024){
            const unsigned u = kk[cd[i]];
            if ((u >> 10) == top22) atomicAdd(&lh[u & 0x3FFu], 1u);
        }
    }
    __syncthreads();
    if (tid < 32){ unsigned s = 0; for (int j = 0; j < 32; ++j) s += lh[tid*32+j]; coarse[tid] = s; }
    __syncthreads();
    if (tid == 0){
        unsigned kneed = kneed2, cum = 0; int cb = 31;
        for (; cb > 0; --cb){ if (cum + coarse[cb] >= kneed) break; cum += coarse[cb]; }
        int bin = cb*32 + 31;
        for (; bin > cb*32; --bin){ if (cum + lh[bin] >= kneed) break; cum += lh[bin]; }
        sB[0] = (unsigned)bin; sB[1] = kneed - cum;
    }
    __syncthreads();
    const unsigned B3 = sB[0], take_eq = sB[1];
    const unsigned utar = (B1 << 21) | (B2 << 10) | B3;
    __syncthreads();

    // phase T1: hist of idx>>7 among ties (ascending)
    for (int i = tid; i < 1024; i += 1024) lh[i] = 0u;
    __syncthreads();
    for (int ch2 = 0; ch2 < CHUNKS; ++ch2){
        const int n = (int)nccs[ch2]; const int* cd = cd0 + ch2*SUBCAP;
        for (int i = tid; i < n; i += 1024){
            const int ix = cd[i];
            if (kk[ix] == utar) atomicAdd(&lh[ix >> 7], 1u);
        }
    }
    __syncthreads();
    if (tid < 32){ unsigned s = 0; for (int j = 0; j < 32; ++j) s += lh[tid*32+j]; coarse[tid] = s; }
    __syncthreads();
    if (tid == 0){
        unsigned need = take_eq, cum = 0; int cb = 0;
        for (; cb < 31; ++cb){ if (cum + coarse[cb] >= need) break; cum += coarse[cb]; }
        int bin = cb*32;
        for (; bin < cb*32+31; ++bin){ if (cum + lh[bin] >= need) break; cum += lh[bin]; }
        sB[0] = (unsigned)bin; sB[1] = need - cum;
    }
    __syncthreads();
    const unsigned cb7 = sB[0], rem = sB[1];
    __syncthreads();

    // phase T2: low 7 index bits (ascending)
    for (int i = tid; i < 128; i += 1024) lh[i] = 0u;
    __syncthreads();
    for (int ch2 = 0; ch2 < CHUNKS; ++ch2){
        const int n = (int)nccs[ch2]; const int* cd = cd0 + ch2*SUBCAP;
        for (int i = tid; i < n; i += 1024){
            const int ix = cd[i];
            if (kk[ix] == utar && (unsigned)(ix >> 7) == cb7) atomicAdd(&lh[ix & 127], 1u);
        }
    }
    __syncthreads();
    if (tid == 0){
        unsigned need = rem, cum = 0; int p = 0;
        for (; p < 127; ++p){ if (cum + lh[p] >= need) break; cum += lh[p]; }
        gParams[g*8+2] = utar;
        gParams[g*8+3] = cb7*128 + (unsigned)p;   // T
    }
}

// ---------------------------------------------------------------------------
// Kernel 3: mask write + compact list output + fused gather into fp64 partial
// sums. (proven)
// ---------------------------------------------------------------------------
__global__ __launch_bounds__(1024) void write_gather_kernel(
        const unsigned* __restrict__ keys, const unsigned* __restrict__ gParams,
        const float* __restrict__ x, unsigned char* __restrict__ mask,
        int* __restrict__ lists, unsigned* __restrict__ gListCnt,
        double* __restrict__ part, int N, int R)
{
    const int g = blockIdx.x / WCH, c = blockIdx.x % WCH;
    const int b = g >> 1, v = g & 1;
    const unsigned* kk = keys + (size_t)v * N + (size_t)b * R;
    unsigned char* mk = mask + (size_t)v * N + (size_t)b * R;
    int* lst = lists + g * KSEL;
    const unsigned utar = gParams[g*8+2];
    const int T = (int)gParams[g*8+3];
    const int tid = threadIdx.x, wave = tid >> 6, lane = tid & 63;
    const int s = tid >> 5;              // row slot 0..31
    const int c4 = (tid & 31) * 4;       // column group
    const float* xb = x + (size_t)b * R * N_IN;

    __shared__ int slist[1024];
    __shared__ unsigned wcnt[16];
    __shared__ unsigned sSubBase;
    __shared__ double red[32][128];

    double a0 = 0.0, a1 = 0.0, a2 = 0.0, a3 = 0.0;

    for (int sub = 0; sub < 8; ++sub){
        const int i = c*8192 + sub*1024 + tid;
        const bool valid = i < R;
        const unsigned u = valid ? kk[i] : 0u;
        const bool sel = valid && (u > utar || (u == utar && i <= T));
        if (valid) mk[i] = sel ? (unsigned char)1 : (unsigned char)0;
        unsigned long long m = __ballot(sel);
        if (lane == 0) wcnt[wave] = (unsigned)__popcll(m);
        __syncthreads();
        unsigned pre = 0, tot = 0;
        #pragma unroll
        for (int w = 0; w < 16; ++w){ unsigned cc = wcnt[w]; if (w < wave) pre += cc; tot += cc; }
        if (tid == 0) sSubBase = tot ? atomicAdd(&gListCnt[g*16], tot) : 0u;
        const unsigned loc = pre + (unsigned)__popcll(m & ((1ULL << lane) - 1ULL));
        if (sel) slist[loc] = i;
        __syncthreads();
        if (sel) lst[sSubBase + loc] = i;
        for (int rr = s; rr < (int)tot; rr += 32){
            const float4 xv = *reinterpret_cast<const float4*>(xb + (size_t)slist[rr] * N_IN + c4);
            a0 += xv.x; a1 += xv.y; a2 += xv.z; a3 += xv.w;
        }
        __syncthreads();
    }

    // cross-slot reduce
    red[s][c4+0] = a0; red[s][c4+1] = a1; red[s][c4+2] = a2; red[s][c4+3] = a3;
    __syncthreads();
    #pragma unroll
    for (int stride = 16; stride >= 1; stride >>= 1){
        if (s < stride){
            red[s][c4+0] += red[s+stride][c4+0];
            red[s][c4+1] += red[s+stride][c4+1];
            red[s][c4+2] += red[s+stride][c4+2];
            red[s][c4+3] += red[s+stride][c4+3];
        }
        __syncthreads();
    }
    if (s == 0){
        double* pp = part + ((size_t)g * WCH + c) * N_IN;
        pp[c4+0] = red[0][c4+0]; pp[c4+1] = red[0][c4+1];
        pp[c4+2] = red[0][c4+2]; pp[c4+3] = red[0][c4+3];
    }
}

// ---------------------------------------------------------------------------
// Kernel 4: fused MLP + sparse blend update. Every block redundantly computes
// its batch's tiny MLP (fp64, deterministic, weights L2-resident) into LDS,
// then applies the blend to its slice of the selection list.
// ---------------------------------------------------------------------------
__global__ __launch_bounds__(256) void update_mlp_kernel(
        const float* __restrict__ x, const unsigned char* __restrict__ mask,
        const int* __restrict__ lists, const double* __restrict__ part,
        const float* __restrict__ W1, const float* __restrict__ b1,
        const float* __restrict__ W2, const float* __restrict__ b2,
        float* __restrict__ out, int N, int R)
{
    const int g = blockIdx.x >> 4, sl = blockIdx.x & (USLICE-1);
    const int b = g >> 1, v = g & 1;
    const int tid = threadIdx.x;

    __shared__ __align__(16) float inv[DD];
    __shared__ __align__(16) float h1s[DD];
    __shared__ __align__(16) float u[DD];

    // inv = virt/K for this batch (both virtual nodes)
    {
        const int g2 = b*2 + (tid >> 7);
        const int fcol = tid & 127;
        double s = 0.0;
        for (int cc = 0; cc < WCH; ++cc) s += part[((size_t)g2 * WCH + cc) * N_IN + fcol];
        inv[tid] = (float)(s / (double)KSEL);
    }
    __syncthreads();
    {
        double a0=0, a1=0, a2=0, a3=0;
        for (int i = 0; i < DD; i += 4){
            a0 += (double)inv[i+0] * (double)W1[(i+0)*DD + tid];
            a1 += (double)inv[i+1] * (double)W1[(i+1)*DD + tid];
            a2 += (double)inv[i+2] * (double)W1[(i+2)*DD + tid];
            a3 += (double)inv[i+3] * (double)W1[(i+3)*DD + tid];
        }
        h1s[tid] = fmaxf((float)(((a0+a1)+(a2+a3)) + (double)b1[tid]), 0.0f);
    }
    __syncthreads();
    {
        double a0=0, a1=0, a2=0, a3=0;
        for (int i = 0; i < DD; i += 4){
            a0 += (double)h1s[i+0] * (double)W2[(i+0)*DD + tid];
            a1 += (double)h1s[i+1] * (double)W2[(i+1)*DD + tid];
            a2 += (double)h1s[i+2] * (double)W2[(i+2)*DD + tid];
            a3 += (double)h1s[i+3] * (double)W2[(i+3)*DD + tid];
        }
        u[tid] = (float)(((a0+a1)+(a2+a3)) + (double)b2[tid]);
    }
    __syncthreads();

    // sparse blend on this slice of the selection list
    const int wave = tid >> 6, lane = tid & 63;
    const int half = lane >> 5;
    const int c4 = (lane & 31) * 4;
    const int* lst = lists + g * KSEL + sl * (KSEL/USLICE);
    const unsigned char* mk0 = mask + (size_t)b * R;
    const unsigned char* mk1 = mask + (size_t)N + (size_t)b * R;
    const float4 u0 = *reinterpret_cast<const float4*>(&u[c4]);
    const float4 u1 = *reinterpret_cast<const float4*>(&u[128 + c4]);
    const size_t rowBase = (size_t)b * R;

    for (int e = wave*2 + half; e < KSEL/USLICE; e += 8){
        const int row = lst[e];
        if (v == 1 && mk0[row]) continue;          // handled by the v0 pass
        const size_t base = (rowBase + row) * N_IN + c4;
        float4 o = *reinterpret_cast<const float4*>(x + base);
        if (v == 0){
            o.x = (o.x + u0.x)*0.5f; o.y = (o.y + u0.y)*0.5f;
            o.z = (o.z + u0.z)*0.5f; o.w = (o.w + u0.w)*0.5f;
            if (mk1[row]){
                o.x = (o.x + u1.x)*0.5f; o.y = (o.y + u1.y)*0.5f;
                o.z = (o.z + u1.z)*0.5f; o.w = (o.w + u1.w)*0.5f;
            }
        } else {
            o.x = (o.x + u1.x)*0.5f; o.y = (o.y + u1.y)*0.5f;
            o.z = (o.z + u1.z)*0.5f; o.w = (o.w + u1.w)*0.5f;
        }
        *reinterpret_cast<float4*>(out + base) = o;
    }
}

extern "C" void kernel_launch(void* const* d_in, const int* in_sizes, int n_in_cnt,
                              void* d_out, int out_size, void* d_ws, size_t ws_size,
                              hipStream_t stream)
{
    const float* x    = (const float*)d_in[0];
    const float* W_fr = (const float*)d_in[1];
    const float* b_fr = (const float*)d_in[2];
    const float* W1   = (const float*)d_in[3];
    const float* b1   = (const float*)d_in[4];
    const float* W2   = (const float*)d_in[5];
    const float* b2   = (const float*)d_in[6];
    float* out = (float*)d_out;

    const int N = in_sizes[0] / N_IN;   // 800000
    const int R = N / NBATCH;           // 100000

    char* ws = (char*)d_ws;
    size_t off = 0;
    auto alloc = [&](size_t bytes) -> void* {
        void* p = ws + off;
        off = (off + bytes + 255) & ~(size_t)255;
        return p;
    };
    unsigned char* mask = (unsigned char*)alloc((size_t)2 * N);
    int*      lists   = (int*)     alloc((size_t)NGROUP * KSEL * 4);
    double*   part    = (double*)  alloc((size_t)NGROUP * WCH * N_IN * 8);
    unsigned* gParams = (unsigned*)alloc((size_t)NGROUP * 8 * 4);
    unsigned* gCandCnt= (unsigned*)alloc((size_t)NGROUP * CHUNKS * 4);

    const size_t zrBytes = 256 + 4096 + (size_t)NGROUP * HSLOTS * 2048 * 4;
    char*     zr       = (char*)    alloc(zrBytes);
    unsigned* gDone    = (unsigned*)zr;                  // 16 counters
    unsigned* gListCnt = (unsigned*)(zr + 256);          // 16 groups * 64B lines
    unsigned* gHist    = (unsigned*)(zr + 256 + 4096);
    unsigned* keys     = (unsigned*)alloc((size_t)2 * N * 4);
    int*      cand     = (int*)     alloc((size_t)NGROUP * CAND_CAP * 4);

    const int n16 = (int)(zrBytes / 16);
    zero_kernel<<<dim3((n16 + 255) / 256), dim3(256), 0, stream>>>((uint4*)zr, n16);
    scores_hist_copy_kernel<<<dim3(NBATCH*K1_CPB), dim3(256), 0, stream>>>(
        x, W_fr, b_fr, keys, gHist, out, N, R);
    collect_refine_kernel<<<dim3(NGROUP*CHUNKS), dim3(1024), 0, stream>>>(
        keys, gHist, gCandCnt, cand, gParams, gDone, N, R);
    write_gather_kernel<<<dim3(NGROUP*WCH), dim3(1024), 0, stream>>>(
        keys, gParams, x, mask, lists, gListCnt, part, N, R);
    update_mlp_kernel<<<dim3(NGROUP*USLICE), dim3(256), 0, stream>>>(
        x, mask, lists, part, W1, b1, W2, b2, out, N, R);
}